// Round 6
// baseline (1143.626 us; speedup 1.0000x reference)
//
#include <hip/hip_runtime.h>
#include <hip/hip_bf16.h>

#define N_GRAPHS 64
#define TPAD 68     // padded LDS row stride (floats)
#define NT 16       // src tiles (src >> TSHIFT)
#define TSHIFT 13   // 8192 nodes/tile

// ---------------- bucket-level histogram (bucket = dst>>8) ----------------

#define EBH 8192
__global__ void bucket_hist_kernel(const int* __restrict__ dst, int* __restrict__ bcnt,
                                   int E, int nbuck) {
    __shared__ int lh[512];
    const int tid = threadIdx.x;
    for (int i = tid; i < nbuck; i += 256) lh[i] = 0;
    __syncthreads();
    const int e0 = blockIdx.x * EBH;
    const int e1 = min(e0 + EBH, E);
    for (int e = e0 + tid; e < e1; e += 256)
        atomicAdd(&lh[((unsigned)dst[e]) >> 8], 1);
    __syncthreads();
    for (int i = tid; i < nbuck; i += 256) {
        int c = lh[i];
        if (c) atomicAdd(&bcnt[i], c);
    }
}

// exclusive scan of bucket counts (nbuck <= 512), seed bucket cursors
__global__ void bucket_scan_kernel(const int* __restrict__ bcnt, int* __restrict__ bbase,
                                   int* __restrict__ bcur, int nbuck) {
    __shared__ int sh[512];
    const int tid = threadIdx.x;
    int v = (tid < nbuck) ? bcnt[tid] : 0;
    sh[tid] = v;
    __syncthreads();
    for (int off = 1; off < 512; off <<= 1) {
        int t = (tid >= off) ? sh[tid - off] : 0;
        __syncthreads();
        sh[tid] += t;
        __syncthreads();
    }
    if (tid < nbuck) { int e = sh[tid] - v; bbase[tid] = e; bcur[tid] = e; }
    if (tid == nbuck - 1) bbase[nbuck] = sh[tid];
}

// ---------------- binned scatter: packed edge = (dst&255)<<24 | src ----------------

#define EBC 4096
__global__ void binscatter_kernel(const int* __restrict__ src, const int* __restrict__ dst,
                                  int* __restrict__ bcur, unsigned* __restrict__ binned,
                                  int E, int nbuck) {
    __shared__ int lhist[512];
    __shared__ int lbase[512];
    const int tid = threadIdx.x;
    const int e0 = blockIdx.x * EBC;
    const int e1 = min(e0 + EBC, E);
    for (int i = tid; i < nbuck; i += 256) lhist[i] = 0;
    __syncthreads();
    for (int e = e0 + tid; e < e1; e += 256) atomicAdd(&lhist[((unsigned)dst[e]) >> 8], 1);
    __syncthreads();
    for (int i = tid; i < nbuck; i += 256) {
        int c = lhist[i];
        lbase[i] = (c > 0) ? atomicAdd(&bcur[i], c) : 0;
        lhist[i] = 0;
    }
    __syncthreads();
    for (int e = e0 + tid; e < e1; e += 256) {
        int d = dst[e];
        int b = ((unsigned)d) >> 8;
        int off = atomicAdd(&lhist[b], 1);
        binned[lbase[b] + off] = ((unsigned)(d & 255) << 24) | (unsigned)src[e];
    }
}

// ---------------- per-bucket: deg/rs/dis/Xs + (node,srctile)-ordered CSR ----------------

__global__ void build_bucket_kernel(const unsigned* __restrict__ binned, const int* __restrict__ bbase,
                                    const float* __restrict__ x, int* __restrict__ rs,
                                    float* __restrict__ dis_g, float* __restrict__ Xs,
                                    int* __restrict__ col, int n) {
    __shared__ int cnt2[256 * NT];   // per (node-in-bucket, srctile) count -> cursor
    __shared__ int wsum[4];
    const int b = blockIdx.x;
    const int node_base = b << 8;
    const int nb = min(256, n - node_base);
    const int tid = threadIdx.x;
    #pragma unroll
    for (int t = 0; t < NT; ++t) cnt2[tid * NT + t] = 0;
    __syncthreads();
    const int e0 = bbase[b], e1 = bbase[b + 1];
    for (int e = e0 + tid; e < e1; e += 256) {
        unsigned v = binned[e];
        int dloc = v >> 24;
        int t = (int)((v & 0xFFFFFFu) >> TSHIFT);
        atomicAdd(&cnt2[dloc * NT + t], 1);
    }
    __syncthreads();
    int deg = 0;
    #pragma unroll
    for (int t = 0; t < NT; ++t) deg += cnt2[tid * NT + t];
    const int lane = tid & 63, wid = tid >> 6;
    int s = deg;
    #pragma unroll
    for (int off = 1; off < 64; off <<= 1) {
        int t = __shfl_up(s, off);
        if (lane >= off) s += t;
    }
    if (lane == 63) wsum[wid] = s;
    __syncthreads();
    int woff = 0;
    for (int w = 0; w < wid; ++w) woff += wsum[w];
    const int excl = woff + s - deg;
    int run = e0 + excl;
    #pragma unroll
    for (int t = 0; t < NT; ++t) {
        int c = cnt2[tid * NT + t];
        cnt2[tid * NT + t] = run;
        run += c;
    }
    if (tid < nb) {
        int node = node_base + tid;
        rs[node] = e0 + excl;
        float d = rsqrtf((float)deg + 1.0f);
        dis_g[node] = d;
        float4 xv = *(const float4*)&x[node * 4];
        *(float4*)&Xs[node * 4] = make_float4(d * xv.x, d * xv.y, d * xv.z, d * xv.w);
    }
    if (tid == 0 && node_base + nb == n) rs[n] = e1;
    __syncthreads();
    for (int e = e0 + tid; e < e1; e += 256) {
        unsigned v = binned[e];
        int dloc = v >> 24;
        int srcv = (int)(v & 0xFFFFFFu);
        int t = srcv >> TSHIFT;
        int p = atomicAdd(&cnt2[dloc * NT + t], 1);
        col[p] = srcv;
    }
}

// ---------------- layer 1: aggregate x (4-dim) ----------------

__global__ void agg4_kernel(const float* __restrict__ Xs, const int* __restrict__ col,
                            const int* __restrict__ rs, const float* __restrict__ dis,
                            float* __restrict__ aggX, int n) {
    int i = blockIdx.x * blockDim.x + threadIdx.x;
    if (i >= n) return;
    int e = rs[i];
    const int end = rs[i + 1];
    float4 a0 = make_float4(0, 0, 0, 0), a1 = make_float4(0, 0, 0, 0);
    for (; e + 2 <= end; e += 2) {
        int s0 = col[e], s1 = col[e + 1];
        float4 v0 = *(const float4*)&Xs[s0 * 4];
        float4 v1 = *(const float4*)&Xs[s1 * 4];
        a0.x += v0.x; a0.y += v0.y; a0.z += v0.z; a0.w += v0.w;
        a1.x += v1.x; a1.y += v1.y; a1.z += v1.z; a1.w += v1.w;
    }
    if (e < end) {
        float4 v = *(const float4*)&Xs[col[e] * 4];
        a0.x += v.x; a0.y += v.y; a0.z += v.z; a0.w += v.w;
    }
    float4 self = *(const float4*)&Xs[i * 4];
    float d = dis[i];
    float4 r = make_float4(d * (a0.x + a1.x + self.x), d * (a0.y + a1.y + self.y),
                           d * (a0.z + a1.z + self.z), d * (a0.w + a1.w + self.w));
    *(float4*)&aggX[i * 4] = r;
}

// ---------------- fused layer-1 transform + layer-2 pre-transform ----------------
// T[i] = dis[i] * ( relu(aggX[i] @ W1 + b1) @ W2 )

__global__ void fused_l1_kernel(const float* __restrict__ aggX, const float* __restrict__ W1,
                                const float* __restrict__ b1, const float* __restrict__ W2,
                                const float* __restrict__ dis, float* __restrict__ t, int n) {
    __shared__ float W1s[256];
    __shared__ float b1s[64];
    __shared__ float Wt[64 * TPAD];
    __shared__ float Hs[64 * TPAD];
    const int tid = threadIdx.x;
    const int base = blockIdx.x * 64;
    if (tid < 256) W1s[tid] = W1[tid];
    if (tid < 64) b1s[tid] = b1[tid];
    for (int idx = tid; idx < 4096; idx += 256) {
        int k = idx >> 6, f = idx & 63;
        Wt[f * TPAD + k] = W2[idx];
    }
    __syncthreads();
    for (int idx = tid; idx < 4096; idx += 256) {
        int nn = idx >> 6, k = idx & 63;
        int node = base + nn;
        float v = 0.0f;
        if (node < n) {
            float4 a = *(const float4*)&aggX[node * 4];
            v = fmaxf(a.x * W1s[k] + a.y * W1s[64 + k] + a.z * W1s[128 + k] + a.w * W1s[192 + k]
                      + b1s[k], 0.0f);
        }
        Hs[nn * TPAD + k] = v;
    }
    __syncthreads();
    const int tf = tid & 15;
    const int tn = tid >> 4;
    float acc[4][4] = {};
    for (int k = 0; k < 64; k += 4) {
        float4 w4[4], h4[4];
        #pragma unroll
        for (int ff = 0; ff < 4; ++ff) w4[ff] = *(const float4*)&Wt[(tf * 4 + ff) * TPAD + k];
        #pragma unroll
        for (int nn = 0; nn < 4; ++nn) h4[nn] = *(const float4*)&Hs[(tn * 4 + nn) * TPAD + k];
        #pragma unroll
        for (int nn = 0; nn < 4; ++nn)
            #pragma unroll
            for (int ff = 0; ff < 4; ++ff)
                acc[nn][ff] += h4[nn].x * w4[ff].x + h4[nn].y * w4[ff].y +
                               h4[nn].z * w4[ff].z + h4[nn].w * w4[ff].w;
    }
    #pragma unroll
    for (int nn = 0; nn < 4; ++nn) {
        int node = base + tn * 4 + nn;
        if (node < n) {
            float d = dis[node];
            float4 o = make_float4(d * acc[nn][0], d * acc[nn][1], d * acc[nn][2], d * acc[nn][3]);
            *(float4*)&t[node * 64 + tf * 4] = o;
        }
    }
}

// ---------------- persistent, tile-phase-aligned aggregation ----------------
// 1024 blocks x 4 waves, all resident (4 blocks/CU). Each wave owns NPW node
// slots (F=64: 1 node/slot, all 64 lanes; F=32: 2 nodes/slot via half-waves).
// Cursors+accumulators in registers; the 16 src-tile phases execute in
// near-lockstep chip-wide so each phase's gathers hit a ~2MB L2-resident tile.
// FUSE_W3 epilogue: r=relu(dis*(acc+self)+bias); out = dis*(r@W3)  [64->32]
// else:             out = dis*(acc+self) + bias                    [F-dim]

template <int F, int NPW, bool FUSE_W3>
__global__ __launch_bounds__(256, 4)
void agg_tiled_kernel(const float* __restrict__ t, const int* __restrict__ col,
                      const int* __restrict__ rs, const float* __restrict__ dis,
                      const float* __restrict__ bias, const float* __restrict__ W3,
                      float* __restrict__ out, int n) {
    __shared__ float W3s[2048];
    __shared__ float rowbuf[4][2][64];
    const int tid = threadIdx.x;
    if (FUSE_W3) {
        for (int idx = tid; idx < 2048; idx += 256) W3s[idx] = W3[idx];
        __syncthreads();
    }
    const int lane = tid & 63;
    const int w = tid >> 6;
    const int gw = blockIdx.x * 4 + w;
    const int h = (F == 64) ? 0 : (lane >> 5);
    const int f = lane & (F - 1);
    const int npn = 64 / F;
    const int base = gw * NPW * npn;

    int cur[NPW], endr[NPW];
    float acc[NPW];
    #pragma unroll
    for (int k = 0; k < NPW; ++k) {
        int i = base + k * npn + h;
        bool valid = (i < n);
        cur[k] = valid ? rs[i] : 0;
        endr[k] = valid ? rs[i + 1] : 0;
        acc[k] = 0.0f;
    }

    for (int tp = 0; tp < NT; ++tp) {
        #pragma unroll
        for (int k = 0; k < NPW; ++k) {
            int e = cur[k];
            const int en = endr[k];
            while (e < en) {
                int s = col[e];
                if ((s >> TSHIFT) != tp) break;
                acc[k] += t[s * F + f];
                ++e;
            }
            cur[k] = e;
        }
    }

    if (FUSE_W3) {
        const int hh = lane >> 5, c = lane & 31;
        #pragma unroll
        for (int k = 0; k < NPW; k += 2) {
            const int i0 = base + k;
            const int i1 = base + k + 1;
            float d0 = 0.0f, d1 = 0.0f;
            float r0 = 0.0f, r1 = 0.0f;
            if (i0 < n) { d0 = dis[i0]; r0 = fmaxf(d0 * (acc[k] + t[i0 * 64 + f]) + bias[f], 0.0f); }
            if (k + 1 < NPW && i1 < n) { d1 = dis[i1]; r1 = fmaxf(d1 * (acc[k + 1] + t[i1 * 64 + f]) + bias[f], 0.0f); }
            rowbuf[w][0][lane] = r0;
            rowbuf[w][1][lane] = r1;
            __syncthreads();   // uniform trip count across all waves
            const int ii = (hh == 0) ? i0 : i1;
            const bool wr = (hh == 0) ? (i0 < n) : (k + 1 < NPW && i1 < n);
            if (wr) {
                float dot = 0.0f;
                #pragma unroll
                for (int ff = 0; ff < 64; ++ff) dot += rowbuf[w][hh][ff] * W3s[ff * 32 + c];
                out[ii * 32 + c] = ((hh == 0) ? d0 : d1) * dot;
            }
            __syncthreads();
        }
    } else {
        #pragma unroll
        for (int k = 0; k < NPW; ++k) {
            int i = base + k * npn + h;
            if (i < n) out[i * F + f] = dis[i] * (acc[k] + t[i * F + f]) + bias[f];
        }
    }
}

// ---------------- readout ----------------

__device__ __forceinline__ unsigned mapf(float v) {
    unsigned u = __float_as_uint(v);
    return u ^ ((u & 0x80000000u) ? 0xFFFFFFFFu : 0x80000000u);
}

#define MAPPED_NEG_INF 0x007FFFFFu

__global__ void init_readout_kernel(float* __restrict__ gsum, unsigned* __restrict__ gmax,
                                    int* __restrict__ gcnt) {
    int idx = blockIdx.x * blockDim.x + threadIdx.x;
    if (idx < N_GRAPHS * 32) { gsum[idx] = 0.0f; gmax[idx] = MAPPED_NEG_INF; }
    if (idx < N_GRAPHS) gcnt[idx] = 0;
}

#define R_CHUNK 512
__global__ void readout_kernel(const float* __restrict__ emb, const int* __restrict__ batch,
                               float* __restrict__ gsum, unsigned* __restrict__ gmax,
                               int* __restrict__ gcnt, int n) {
    __shared__ float ssum[N_GRAPHS * 32];
    __shared__ unsigned smax[N_GRAPHS * 32];
    __shared__ int scnt[N_GRAPHS];
    const int tid = threadIdx.x;
    for (int idx = tid; idx < N_GRAPHS * 32; idx += 256) { ssum[idx] = 0.0f; smax[idx] = MAPPED_NEG_INF; }
    if (tid < N_GRAPHS) scnt[tid] = 0;
    __syncthreads();
    const int lane = tid & 31, grp = tid >> 5;
    const int start = blockIdx.x * R_CHUNK;
    const int end = min(start + R_CHUNK, n);
    for (int i = start + grp; i < end; i += 8) {
        int g = batch[i];
        float v = emb[i * 32 + lane];
        atomicAdd(&ssum[g * 32 + lane], v);
        atomicMax(&smax[g * 32 + lane], mapf(v));
        if (lane == 0) atomicAdd(&scnt[g], 1);
    }
    __syncthreads();
    for (int idx = tid; idx < N_GRAPHS * 32; idx += 256) {
        int g = idx >> 5;
        if (scnt[g] > 0) {
            atomicAdd(&gsum[idx], ssum[idx]);
            atomicMax(&gmax[idx], smax[idx]);
        }
    }
    if (tid < N_GRAPHS && scnt[tid] > 0) atomicAdd(&gcnt[tid], scnt[tid]);
}

__global__ void finalize_kernel(const float* __restrict__ gsum, const unsigned* __restrict__ gmax,
                                const int* __restrict__ gcnt, float* __restrict__ out) {
    int idx = blockIdx.x * blockDim.x + threadIdx.x;
    if (idx >= N_GRAPHS * 32) return;
    int g = idx >> 5, f = idx & 31;
    float c = fmaxf((float)gcnt[g], 1.0f);
    out[g * 64 + f] = gsum[idx] / c;
    unsigned u = gmax[idx];
    unsigned bits = (u & 0x80000000u) ? (u ^ 0x80000000u) : ~u;
    out[g * 64 + 32 + f] = __uint_as_float(bits);
}

// ---------------- launch ----------------

extern "C" void kernel_launch(void* const* d_in, const int* in_sizes, int n_in,
                              void* d_out, int out_size, void* d_ws, size_t ws_size,
                              hipStream_t stream) {
    const float* x  = (const float*)d_in[0];
    const float* W1 = (const float*)d_in[1];
    const float* b1 = (const float*)d_in[2];
    const float* W2 = (const float*)d_in[3];
    const float* b2 = (const float*)d_in[4];
    const float* W3 = (const float*)d_in[5];
    const float* b3 = (const float*)d_in[6];
    const int* edge_index = (const int*)d_in[7];
    const int* batch = (const int*)d_in[8];
    float* out = (float*)d_out;

    const int N = in_sizes[0] / 4;
    const int E = in_sizes[7] / 2;
    const int* src = edge_index;
    const int* dst = edge_index + E;
    const int nbuck = (N + 255) >> 8;    // <= 512

    // workspace carve-up (256B aligned)
    char* p = (char*)d_ws;
    auto alloc = [&](size_t bytes) { void* r = (void*)p; p += (bytes + 255) & ~(size_t)255; return r; };
    int*      rs   = (int*)alloc((size_t)(N + 1) * 4);
    float*    dis  = (float*)alloc((size_t)N * 4);
    int*      col  = (int*)alloc((size_t)E * 4);
    float*    Xs   = (float*)alloc((size_t)N * 4 * 4);
    float*    aggX = (float*)alloc((size_t)N * 4 * 4);
    float*    T    = (float*)alloc((size_t)N * 64 * 4);   // also: binned (E ints), later H32 (N*32)
    float*    T32  = (float*)alloc((size_t)N * 32 * 4);
    int*      bcnt = (int*)alloc((size_t)512 * 4);
    int*      bbase= (int*)alloc((size_t)513 * 4);
    int*      bcur = (int*)alloc((size_t)512 * 4);
    float*    gsum = (float*)alloc((size_t)N_GRAPHS * 32 * 4);
    unsigned* gmax = (unsigned*)alloc((size_t)N_GRAPHS * 32 * 4);
    int*      gcnt = (int*)alloc((size_t)N_GRAPHS * 4);
    unsigned* binned = (unsigned*)T;   // consumed by build_bucket before fused_l1 writes T
    float*    H32    = T;              // written after T is dead
    (void)ws_size; (void)n_in; (void)out_size;

    const int gN = (N + 255) / 256;

    // CSR build (dst-bucket binned, then per-(node,srctile) counting sort)
    hipMemsetAsync(bcnt, 0, 512 * 4, stream);
    bucket_hist_kernel<<<(E + EBH - 1) / EBH, 256, 0, stream>>>(dst, bcnt, E, nbuck);
    bucket_scan_kernel<<<1, 512, 0, stream>>>(bcnt, bbase, bcur, nbuck);
    binscatter_kernel<<<(E + EBC - 1) / EBC, 256, 0, stream>>>(src, dst, bcur, binned, E, nbuck);
    build_bucket_kernel<<<nbuck, 256, 0, stream>>>(binned, bbase, x, rs, dis, Xs, col, N);

    // layer 1 aggregate + fused (W1,relu,b1,W2,dis) transform
    agg4_kernel<<<gN, 256, 0, stream>>>(Xs, col, rs, dis, aggX, N);
    fused_l1_kernel<<<(N + 63) / 64, 256, 0, stream>>>(aggX, W1, b1, W2, dis, T, N);
    // layer 2 aggregate (persistent, phase-aligned) fused with W3 -> T32
    agg_tiled_kernel<64, 25, true><<<1024, 256, 0, stream>>>(T, col, rs, dis, b2, W3, T32, N);
    // layer 3 aggregate (persistent, phase-aligned)
    agg_tiled_kernel<32, 13, false><<<1024, 256, 0, stream>>>(T32, col, rs, dis, b3, W3, H32, N);

    // readout
    init_readout_kernel<<<(N_GRAPHS * 32 + 255) / 256, 256, 0, stream>>>(gsum, gmax, gcnt);
    readout_kernel<<<(N + R_CHUNK - 1) / R_CHUNK, 256, 0, stream>>>(H32, batch, gsum, gmax, gcnt, N);
    finalize_kernel<<<(N_GRAPHS * 32 + 255) / 256, 256, 0, stream>>>(gsum, gmax, gcnt, out);
}